// Round 10
// baseline (182.006 us; speedup 1.0000x reference)
//
#include <hip/hip_runtime.h>
#include <math.h>

#define HID   128
#define KTOT  256
#define PREDN 40
#define BM    32
#define AS_STRIDE 264   // ushorts: 256 + 8 pad; 528B rows keep 16B align
#define HS_STRIDE 136   // 128 + 8 pad
#define LG_STRIDE 48
#define CUR_STRIDE 16   // ints: one 64B line per bucket counter
#define EPT   16        // edges per thread in bin branch
#define BSHIFT 10       // 1024 nodes per coarse bucket
#define ROWMASK 0x1FFFF // low 17 bits = emb row (N < 131072)

typedef __attribute__((ext_vector_type(8))) short bf16x8;
typedef __attribute__((ext_vector_type(4))) float f32x4;
typedef __attribute__((ext_vector_type(2))) float f32x2;
typedef __attribute__((ext_vector_type(4))) unsigned short us4;
typedef __attribute__((ext_vector_type(8))) unsigned short us8;

__device__ __forceinline__ unsigned short f2bf(float f) {
  unsigned int u = __float_as_uint(f);
  u = (u + 0x7FFFu + ((u >> 16) & 1u)) >> 16;   // round-to-nearest-even
  return (unsigned short)u;
}
__device__ __forceinline__ float bf2f(unsigned short b) {
  return __uint_as_float(((unsigned int)b) << 16);
}

// accumulate 2 bf16 (packed in one uint) into an f32 pair with one v_pk_add_f32
__device__ __forceinline__ void acc_pk(f32x2& acc, unsigned int u) {
  f32x2 val;
  val[0] = __uint_as_float(u << 16);
  val[1] = __uint_as_float(u & 0xffff0000u);
  asm("v_pk_add_f32 %0, %0, %1" : "+v"(acc) : "v"(val));
}

// ------------- fused prologue: bin edges | emb->bf16 | weights->bf16 -------------

__global__ void prologue_kernel(const int* __restrict__ ei,
                                const int* __restrict__ nidx,
                                const float* __restrict__ emb,
                                const float* __restrict__ Wmsg,
                                const float* __restrict__ Wnode,
                                const float* __restrict__ Wpred,
                                int* __restrict__ gcur,
                                int* __restrict__ region,
                                unsigned short* __restrict__ emb_bf,
                                unsigned short* __restrict__ Wcat,
                                unsigned short* __restrict__ Wpb,
                                int E, int N, int nbucket, int capb,
                                int ntile, int nconv, int nw) {
  int b = blockIdx.x;
  int t = threadIdx.x;
  if (b < ntile) {
    // --- bin: records packed (local_dst<<17)|row, chunked per WG for full-line writes
    __shared__ int hist[128];
    __shared__ int base[128];
    int tb = b * (256 * EPT);
    if (t < 128) hist[t] = 0;
    __syncthreads();
    int rec[EPT], bk[EPT];
#pragma unroll
    for (int j = 0; j < EPT; ++j) {
      int idx = tb + j * 256 + t;
      if (idx < E) {
        int d = __builtin_nontemporal_load(ei + E + idx);
        int s = __builtin_nontemporal_load(ei + idx);
        int r = nidx[s];
        bk[j] = d >> BSHIFT;
        rec[j] = ((d & ((1 << BSHIFT) - 1)) << 17) | r;
        atomicAdd(&hist[bk[j]], 1);
      } else {
        bk[j] = -1;
      }
    }
    __syncthreads();
    if (t < nbucket && hist[t] > 0) base[t] = atomicAdd(&gcur[t * CUR_STRIDE], hist[t]);
    __syncthreads();
    if (t < 128) hist[t] = 0;     // reuse as intra-chunk cursor
    __syncthreads();
#pragma unroll
    for (int j = 0; j < EPT; ++j) {
      if (bk[j] >= 0) {
        int pos = base[bk[j]] + atomicAdd(&hist[bk[j]], 1);
        if (pos < capb) region[(size_t)bk[j] * capb + pos] = rec[j];
      }
    }
  } else if (b < ntile + nconv) {
    // --- emb fp32 -> bf16 (nontemporal read: one-touch stream)
    int i = (b - ntile) * 256 + t;
    int stride = nconv * 256;
    int total4 = N * (HID / 4);
    for (; i < total4; i += stride) {
      f32x4 v = __builtin_nontemporal_load(reinterpret_cast<const f32x4*>(emb) + i);
      us4 o;
      o.x = f2bf(v[0]); o.y = f2bf(v[1]); o.z = f2bf(v[2]); o.w = f2bf(v[3]);
      reinterpret_cast<us4*>(emb_bf)[i] = o;
    }
  } else {
    // --- weights -> bf16 (Wcat = [Wmsg|Wnode] K-major, Wpb = Wpred padded to 48)
    int i = (b - ntile - nconv) * 256 + t;
    int stride = nw * 256;
    for (; i < 128 * 256 + 48 * 128; i += stride) {
      if (i < 128 * 256) {
        int j = i >> 8, k = i & 255;
        float v = (k < HID) ? Wmsg[j * HID + k] : Wnode[j * HID + (k - HID)];
        Wcat[i] = f2bf(v);
      } else {
        int u = i - 128 * 256;
        int p = u >> 7, k = u & 127;
        Wpb[u] = (p < PREDN) ? f2bf(Wpred[p * HID + k]) : (unsigned short)0;
      }
    }
  }
}

// ------------- refine: coarse bucket -> compact per-node CSR (one WG/bucket) -------------

__global__ void refine_kernel(const int* __restrict__ region,
                              const int* __restrict__ gcur,
                              int* __restrict__ csr_rows,
                              int* __restrict__ row_start,
                              int* __restrict__ degv,
                              int N, int capb) {
  __shared__ int hist[1 << BSHIFT];
  __shared__ int cur[1 << BSHIFT];
  __shared__ int ts[256];
  int b = blockIdx.x, t = threadIdx.x;
  int node_base = b << BSHIFT;
  const int nper = 1 << BSHIFT;
  int cnt_b = gcur[b * CUR_STRIDE];
  if (cnt_b > capb) cnt_b = capb;
  const int* reg = region + (size_t)b * capb;

  for (int i = t; i < nper; i += 256) hist[i] = 0;
  __syncthreads();
  for (int i = t; i < cnt_b; i += 256)
    atomicAdd(&hist[reg[i] >> 17], 1);
  __syncthreads();

  int h0 = hist[t * 4], h1 = hist[t * 4 + 1], h2 = hist[t * 4 + 2], h3 = hist[t * 4 + 3];
  int tsum = h0 + h1 + h2 + h3;
  ts[t] = tsum;
  __syncthreads();
  int v = tsum;
  for (int off = 1; off < 256; off <<= 1) {
    int o = (t >= off) ? ts[t - off] : 0;
    __syncthreads();
    v += o;
    ts[t] = v;
    __syncthreads();
  }
  int excl = v - tsum;
  cur[t * 4 + 0] = excl;
  cur[t * 4 + 1] = excl + h0;
  cur[t * 4 + 2] = excl + h0 + h1;
  cur[t * 4 + 3] = excl + h0 + h1 + h2;
  __syncthreads();

  for (int i = t; i < nper; i += 256) {
    int node = node_base + i;
    if (node < N) {
      row_start[node] = b * capb + cur[i];
      degv[node] = hist[i];
    }
  }
  __syncthreads();

  for (int i = t; i < cnt_b; i += 256) {
    int rec = reg[i];
    int pos = atomicAdd(&cur[rec >> 17], 1);
    csr_rows[(size_t)b * capb + pos] = rec & ROWMASK;
  }
}

// ------------- fused: gather-agg + MFMA GEMM + pred + log_softmax -------------

__launch_bounds__(256)
__global__ void fused_node_kernel(const int* __restrict__ csr_rows,
                                  const int* __restrict__ row_start,
                                  const int* __restrict__ degv,
                                  const unsigned short* __restrict__ emb_bf,
                                  const float* __restrict__ feat,
                                  const unsigned short* __restrict__ Wcat,
                                  const unsigned short* __restrict__ Wpb,
                                  const float* __restrict__ bg,
                                  const float* __restrict__ bpred,
                                  float* __restrict__ out, int N) {
  __shared__ __align__(16) unsigned short buf[BM * AS_STRIDE];  // 16896 B
  unsigned short* AsU = buf;
  unsigned short* HsU = buf;                                    // aliased after GEMM1
  float* Lg = (float*)(buf + BM * HS_STRIDE);                   // bytes [8704, 14848)
  int t = threadIdx.x;
  int node0 = blockIdx.x * BM;

  // phase 0: feat -> As[:,128:256) as bf16 (nontemporal: one-touch stream)
  {
    int row = t >> 3, chunk = t & 7;
    int node = node0 + row;
    const f32x4* fp = reinterpret_cast<const f32x4*>(feat + (size_t)node * HID + chunk * 16);
    us8 o0 = {0, 0, 0, 0, 0, 0, 0, 0}, o1 = o0;
    if (node < N) {
      f32x4 f0 = __builtin_nontemporal_load(fp + 0);
      f32x4 f1 = __builtin_nontemporal_load(fp + 1);
      f32x4 f2 = __builtin_nontemporal_load(fp + 2);
      f32x4 f3 = __builtin_nontemporal_load(fp + 3);
      o0[0] = f2bf(f0[0]); o0[1] = f2bf(f0[1]); o0[2] = f2bf(f0[2]); o0[3] = f2bf(f0[3]);
      o0[4] = f2bf(f1[0]); o0[5] = f2bf(f1[1]); o0[6] = f2bf(f1[2]); o0[7] = f2bf(f1[3]);
      o1[0] = f2bf(f2[0]); o1[1] = f2bf(f2[1]); o1[2] = f2bf(f2[2]); o1[3] = f2bf(f2[3]);
      o1[4] = f2bf(f3[0]); o1[5] = f2bf(f3[1]); o1[6] = f2bf(f3[2]); o1[7] = f2bf(f3[3]);
    }
    unsigned short* wp = AsU + row * AS_STRIDE + HID + chunk * 16;
    *reinterpret_cast<us8*>(wp) = o0;
    *reinterpret_cast<us8*>(wp + 8) = o1;
  }

  // phase 1: gather-aggregate — full wave per node, 4 rows per load-instruction,
  // packed f32x2 accumulate (v_pk_add_f32). Group g = lane>>4 takes row i+g.
  int lane = t & 63, wv = t >> 6;
  int g = lane >> 4, l16g = lane & 15;
  for (int nn = wv; nn < BM; nn += 4) {
    int node = node0 + nn;
    f32x2 acc2[4] = {{0.f, 0.f}, {0.f, 0.f}, {0.f, 0.f}, {0.f, 0.f}};
    int cnt = 0;
    if (node < N) {
      cnt = degv[node];
      const int* rows = csr_rows + row_start[node];
      int myrow = (lane < cnt) ? rows[lane] : 0;   // coalesced preload (first 64)
      unsigned coff = (unsigned)(l16g << 4);       // byte offset within row
      int i = 0;
      for (; i + 7 < cnt && i + 7 < 64; i += 8) {
        int rA = __shfl(myrow, i + g);
        int rB = __shfl(myrow, i + 4 + g);
        uint4 uA = *reinterpret_cast<const uint4*>(
            (const char*)emb_bf + (((unsigned)rA << 8) + coff));
        uint4 uB = *reinterpret_cast<const uint4*>(
            (const char*)emb_bf + (((unsigned)rB << 8) + coff));
        acc_pk(acc2[0], uA.x); acc_pk(acc2[1], uA.y);
        acc_pk(acc2[2], uA.z); acc_pk(acc2[3], uA.w);
        acc_pk(acc2[0], uB.x); acc_pk(acc2[1], uB.y);
        acc_pk(acc2[2], uB.z); acc_pk(acc2[3], uB.w);
      }
      for (; i + 3 < cnt; i += 4) {
        int idx = i + g;
        int r = (i + 3 < 64) ? __shfl(myrow, idx & 63) : rows[idx];
        uint4 u = *reinterpret_cast<const uint4*>(
            (const char*)emb_bf + (((unsigned)r << 8) + coff));
        acc_pk(acc2[0], u.x); acc_pk(acc2[1], u.y);
        acc_pk(acc2[2], u.z); acc_pk(acc2[3], u.w);
      }
      int rem = cnt - i;                 // 0..3 tail rows
      if (rem > 0) {
        int idx = i + g;
        int rsh = __shfl(myrow, idx & 63);
        if (g < rem) {
          int r = (idx < 64) ? rsh : rows[idx];
          uint4 u = *reinterpret_cast<const uint4*>(
              (const char*)emb_bf + (((unsigned)r << 8) + coff));
          acc_pk(acc2[0], u.x); acc_pk(acc2[1], u.y);
          acc_pk(acc2[2], u.z); acc_pk(acc2[3], u.w);
        }
      }
    }
#pragma unroll
    for (int k = 0; k < 4; ++k) {
      acc2[k][0] += __shfl_xor(acc2[k][0], 16);
      acc2[k][1] += __shfl_xor(acc2[k][1], 16);
      acc2[k][0] += __shfl_xor(acc2[k][0], 32);
      acc2[k][1] += __shfl_xor(acc2[k][1], 32);
    }
    float inv = 1.0f / fmaxf((float)cnt, 1.0f);
    if (g == 0) {
      us8 o;
#pragma unroll
      for (int k = 0; k < 4; ++k) {
        o[2 * k]     = f2bf(acc2[k][0] * inv);
        o[2 * k + 1] = f2bf(acc2[k][1] * inv);
      }
      *reinterpret_cast<us8*>(AsU + nn * AS_STRIDE + l16g * 8) = o;
    }
  }
  __syncthreads();

  // phase 2: GEMM1 via MFMA 16x16x32 bf16. wave w: colblocks {2w,2w+1}, rowblocks {0,1}
  int w = wv, l16 = lane & 15, quad = lane >> 4;
  f32x4 acc[2][2] = {{{0.f, 0.f, 0.f, 0.f}, {0.f, 0.f, 0.f, 0.f}},
                     {{0.f, 0.f, 0.f, 0.f}, {0.f, 0.f, 0.f, 0.f}}};
#pragma unroll
  for (int kb = 0; kb < 8; ++kb) {
    int ko = kb * 32 + quad * 8;
    bf16x8 a0 = *reinterpret_cast<const bf16x8*>(AsU + l16 * AS_STRIDE + ko);
    bf16x8 a1 = *reinterpret_cast<const bf16x8*>(AsU + (16 + l16) * AS_STRIDE + ko);
    bf16x8 b0 = *reinterpret_cast<const bf16x8*>(Wcat + ((w * 2 + 0) * 16 + l16) * KTOT + ko);
    bf16x8 b1 = *reinterpret_cast<const bf16x8*>(Wcat + ((w * 2 + 1) * 16 + l16) * KTOT + ko);
    acc[0][0] = __builtin_amdgcn_mfma_f32_16x16x32_bf16(a0, b0, acc[0][0], 0, 0, 0);
    acc[0][1] = __builtin_amdgcn_mfma_f32_16x16x32_bf16(a0, b1, acc[0][1], 0, 0, 0);
    acc[1][0] = __builtin_amdgcn_mfma_f32_16x16x32_bf16(a1, b0, acc[1][0], 0, 0, 0);
    acc[1][1] = __builtin_amdgcn_mfma_f32_16x16x32_bf16(a1, b1, acc[1][1], 0, 0, 0);
  }
  __syncthreads();   // all As reads done; buf reusable as Hs

  // bias + relu -> Hs bf16
#pragma unroll
  for (int ci = 0; ci < 2; ++ci) {
    int col = (w * 2 + ci) * 16 + l16;
    float bgv = bg[col];
#pragma unroll
    for (int r = 0; r < 2; ++r)
#pragma unroll
      for (int i = 0; i < 4; ++i) {
        int row = r * 16 + quad * 4 + i;
        float hh = fmaxf(acc[r][ci][i] + bgv, 0.0f);
        HsU[row * HS_STRIDE + col] = f2bf(hh);
      }
  }
  __syncthreads();

  // phase 3: pred head via MFMA (48-col padded), 6 tiles over 4 waves
  for (int tid = w; tid < 6; tid += 4) {
    int r2 = tid & 1, cb = tid >> 1;
    f32x4 acc2p = {0.f, 0.f, 0.f, 0.f};
#pragma unroll
    for (int kb = 0; kb < 4; ++kb) {
      int ko = kb * 32 + quad * 8;
      bf16x8 a = *reinterpret_cast<const bf16x8*>(HsU + (r2 * 16 + l16) * HS_STRIDE + ko);
      bf16x8 b = *reinterpret_cast<const bf16x8*>(Wpb + (cb * 16 + l16) * HID + ko);
      acc2p = __builtin_amdgcn_mfma_f32_16x16x32_bf16(a, b, acc2p, 0, 0, 0);
    }
    int p = cb * 16 + l16;
    if (p < PREDN) {
      float bp = bpred[p];
#pragma unroll
      for (int i = 0; i < 4; ++i)
        Lg[(r2 * 16 + quad * 4 + i) * LG_STRIDE + p] = acc2p[i] + bp;
    }
  }
  __syncthreads();

  // phase 4: log_softmax, half-wave per node (nontemporal out stores)
  int hw = t >> 5, l32 = lane & 31;
  for (int nn = hw; nn < BM; nn += 8) {
    float v0 = Lg[nn * LG_STRIDE + l32];
    float v1 = (l32 < 8) ? Lg[nn * LG_STRIDE + 32 + l32] : -1e30f;
    float m = fmaxf(v0, v1);
    for (int off = 16; off; off >>= 1) m = fmaxf(m, __shfl_xor(m, off, 32));
    float s = expf(v0 - m) + ((l32 < 8) ? expf(v1 - m) : 0.f);
    for (int off = 16; off; off >>= 1) s += __shfl_xor(s, off, 32);
    float lse = m + logf(s);
    int gn = node0 + nn;
    if (gn < N) {
      __builtin_nontemporal_store(v0 - lse, out + (size_t)gn * PREDN + l32);
      if (l32 < 8)
        __builtin_nontemporal_store(v1 - lse, out + (size_t)gn * PREDN + 32 + l32);
    }
  }
}

extern "C" void kernel_launch(void* const* d_in, const int* in_sizes, int n_in,
                              void* d_out, int out_size, void* d_ws, size_t ws_size,
                              hipStream_t stream) {
  const int*   node_index = (const int*)d_in[0];
  const float* node_feat  = (const float*)d_in[1];
  const int*   edge_index = (const int*)d_in[2];
  const float* emb        = (const float*)d_in[3];
  const float* Wmsg       = (const float*)d_in[4];
  const float* Wnode      = (const float*)d_in[5];
  const float* bg         = (const float*)d_in[6];
  const float* Wpred      = (const float*)d_in[7];
  const float* bpred      = (const float*)d_in[8];

  const int N = in_sizes[0];          // 100000
  const int E = in_sizes[2] / 2;      // 1600000

  const int nbucket = (N + (1 << BSHIFT) - 1) >> BSHIFT;       // 98 (<=128)
  int capb = E / nbucket + E / (4 * nbucket) + 2048;           // mean + 25% + slack
  capb = (capb + 15) & ~15;                                    // line-align (16 recs = 64B)

  int* gcur      = (int*)d_ws;                                 // nbucket*CUR_STRIDE
  int* region    = gcur + (size_t)nbucket * CUR_STRIDE;        // nbucket*capb (packed recs)
  int* csr_rows  = region + (size_t)nbucket * capb;            // nbucket*capb
  int* row_start = csr_rows + (size_t)nbucket * capb;          // N
  int* degv      = row_start + N;                              // N
  size_t off = (((size_t)(degv + N) - (size_t)d_ws) + 15) & ~(size_t)15;
  unsigned short* emb_bf = (unsigned short*)((char*)d_ws + off); // N*128
  unsigned short* Wcat   = emb_bf + (size_t)N * HID;             // 128*256
  unsigned short* Wpb    = Wcat + 128 * 256;                     // 48*128

  hipMemsetAsync(gcur, 0, (size_t)nbucket * CUR_STRIDE * sizeof(int), stream);

  const int ntile = (E + 256 * EPT - 1) / (256 * EPT);   // 391
  const int nconv = 416;
  const int nw    = 64;
  prologue_kernel<<<ntile + nconv + nw, 256, 0, stream>>>(
      edge_index, node_index, emb, Wmsg, Wnode, Wpred,
      gcur, region, emb_bf, Wcat, Wpb,
      E, N, nbucket, capb, ntile, nconv, nw);

  refine_kernel<<<nbucket, 256, 0, stream>>>(region, gcur, csr_rows,
                                             row_start, degv, N, capb);

  int nblk = (N + BM - 1) / BM;
  fused_node_kernel<<<nblk, 256, 0, stream>>>(csr_rows, row_start, degv,
                                              emb_bf, node_feat, Wcat, Wpb,
                                              bg, bpred, (float*)d_out, N);
}

// Round 11
// 171.035 us; speedup vs baseline: 1.0641x; 1.0641x over previous
//
#include <hip/hip_runtime.h>
#include <math.h>

#define HID   128
#define KTOT  256
#define PREDN 40
#define BM    32
#define AS_STRIDE 264   // ushorts: 256 + 8 pad; 528B rows keep 16B align
#define HS_STRIDE 136   // 128 + 8 pad
#define LG_STRIDE 48
#define CUR_STRIDE 16   // ints: one 64B line per bucket counter
#define EPT   16        // edges per thread in bin branch
#define BSHIFT 10       // 1024 nodes per coarse bucket
#define ROWMASK 0x1FFFF // low 17 bits = emb row (N < 131072)

typedef __attribute__((ext_vector_type(8))) short bf16x8;
typedef __attribute__((ext_vector_type(4))) float f32x4;
typedef __attribute__((ext_vector_type(2))) float f32x2;
typedef __attribute__((ext_vector_type(4))) unsigned short us4;
typedef __attribute__((ext_vector_type(8))) unsigned short us8;

__device__ __forceinline__ unsigned short f2bf(float f) {
  unsigned int u = __float_as_uint(f);
  u = (u + 0x7FFFu + ((u >> 16) & 1u)) >> 16;   // round-to-nearest-even
  return (unsigned short)u;
}
__device__ __forceinline__ float bf2f(unsigned short b) {
  return __uint_as_float(((unsigned int)b) << 16);
}

// accumulate 2 bf16 (packed in one uint) into an f32 pair with one v_pk_add_f32
__device__ __forceinline__ void acc_pk(f32x2& acc, unsigned int u) {
  f32x2 val;
  val[0] = __uint_as_float(u << 16);
  val[1] = __uint_as_float(u & 0xffff0000u);
  asm("v_pk_add_f32 %0, %0, %1" : "+v"(acc) : "v"(val));
}

// ------------- fused prologue: bin edges | emb->bf16 | weights->bf16 -------------

__global__ void prologue_kernel(const int* __restrict__ ei,
                                const int* __restrict__ nidx,
                                const float* __restrict__ emb,
                                const float* __restrict__ Wmsg,
                                const float* __restrict__ Wnode,
                                const float* __restrict__ Wpred,
                                int* __restrict__ gcur,
                                int* __restrict__ region,
                                unsigned short* __restrict__ emb_bf,
                                unsigned short* __restrict__ Wcat,
                                unsigned short* __restrict__ Wpb,
                                int E, int N, int nbucket, int capb,
                                int ntile, int nconv, int nw) {
  int b = blockIdx.x;
  int t = threadIdx.x;
  if (b < ntile) {
    // --- bin: records packed (local_dst<<17)|row; int4-vectorized edge reads;
    //     per-WG chunk reservation so region writes are full-line.
    __shared__ int hist[128];
    __shared__ int base[128];
    int tb = b * (256 * EPT);
    if (t < 128) hist[t] = 0;
    __syncthreads();
    int rec[EPT], bk[EPT];
#pragma unroll
    for (int p4 = 0; p4 < EPT / 4; ++p4) {
      int idx = tb + p4 * 1024 + t * 4;        // 4 contiguous edges per thread
      if (idx + 3 < E) {
        int4 sv = *reinterpret_cast<const int4*>(ei + idx);
        int4 dv = *reinterpret_cast<const int4*>(ei + E + idx);
        int ss[4] = {sv.x, sv.y, sv.z, sv.w};
        int dd[4] = {dv.x, dv.y, dv.z, dv.w};
#pragma unroll
        for (int q = 0; q < 4; ++q) {
          int j = p4 * 4 + q;
          int d = dd[q];
          bk[j] = d >> BSHIFT;
          rec[j] = ((d & ((1 << BSHIFT) - 1)) << 17) | nidx[ss[q]];
          atomicAdd(&hist[bk[j]], 1);
        }
      } else {
#pragma unroll
        for (int q = 0; q < 4; ++q) {
          int j = p4 * 4 + q;
          int e = idx + q;
          if (e < E) {
            int d = ei[E + e];
            bk[j] = d >> BSHIFT;
            rec[j] = ((d & ((1 << BSHIFT) - 1)) << 17) | nidx[ei[e]];
            atomicAdd(&hist[bk[j]], 1);
          } else {
            bk[j] = -1;
          }
        }
      }
    }
    __syncthreads();
    if (t < nbucket && hist[t] > 0) base[t] = atomicAdd(&gcur[t * CUR_STRIDE], hist[t]);
    __syncthreads();
    if (t < 128) hist[t] = 0;     // reuse as intra-chunk cursor
    __syncthreads();
#pragma unroll
    for (int j = 0; j < EPT; ++j) {
      if (bk[j] >= 0) {
        int pos = base[bk[j]] + atomicAdd(&hist[bk[j]], 1);
        if (pos < capb) region[(size_t)bk[j] * capb + pos] = rec[j];
      }
    }
  } else if (b < ntile + nconv) {
    // --- emb fp32 -> bf16 (plain loads; NT regressed in R9)
    int i = (b - ntile) * 256 + t;
    int stride = nconv * 256;
    int total4 = N * (HID / 4);
    for (; i < total4; i += stride) {
      float4 v = reinterpret_cast<const float4*>(emb)[i];
      us4 o;
      o.x = f2bf(v.x); o.y = f2bf(v.y); o.z = f2bf(v.z); o.w = f2bf(v.w);
      reinterpret_cast<us4*>(emb_bf)[i] = o;
    }
  } else {
    // --- weights -> bf16 (Wcat = [Wmsg|Wnode] K-major, Wpb = Wpred padded to 48)
    int i = (b - ntile - nconv) * 256 + t;
    int stride = nw * 256;
    for (; i < 128 * 256 + 48 * 128; i += stride) {
      if (i < 128 * 256) {
        int j = i >> 8, k = i & 255;
        float v = (k < HID) ? Wmsg[j * HID + k] : Wnode[j * HID + (k - HID)];
        Wcat[i] = f2bf(v);
      } else {
        int u = i - 128 * 256;
        int p = u >> 7, k = u & 127;
        Wpb[u] = (p < PREDN) ? f2bf(Wpred[p * HID + k]) : (unsigned short)0;
      }
    }
  }
}

// ------------- refine: coarse bucket -> compact per-node CSR (one WG/bucket) -------------

__global__ void refine_kernel(const int* __restrict__ region,
                              const int* __restrict__ gcur,
                              int* __restrict__ csr_rows,
                              int* __restrict__ row_start,
                              int* __restrict__ degv,
                              int N, int capb) {
  __shared__ int hist[1 << BSHIFT];
  __shared__ int cur[1 << BSHIFT];
  __shared__ int ts[256];
  int b = blockIdx.x, t = threadIdx.x;
  int node_base = b << BSHIFT;
  const int nper = 1 << BSHIFT;
  int cnt_b = gcur[b * CUR_STRIDE];
  if (cnt_b > capb) cnt_b = capb;
  const int* reg = region + (size_t)b * capb;

  for (int i = t; i < nper; i += 256) hist[i] = 0;
  __syncthreads();
  for (int i = t; i < cnt_b; i += 256)
    atomicAdd(&hist[reg[i] >> 17], 1);
  __syncthreads();

  int h0 = hist[t * 4], h1 = hist[t * 4 + 1], h2 = hist[t * 4 + 2], h3 = hist[t * 4 + 3];
  int tsum = h0 + h1 + h2 + h3;
  ts[t] = tsum;
  __syncthreads();
  int v = tsum;
  for (int off = 1; off < 256; off <<= 1) {
    int o = (t >= off) ? ts[t - off] : 0;
    __syncthreads();
    v += o;
    ts[t] = v;
    __syncthreads();
  }
  int excl = v - tsum;
  cur[t * 4 + 0] = excl;
  cur[t * 4 + 1] = excl + h0;
  cur[t * 4 + 2] = excl + h0 + h1;
  cur[t * 4 + 3] = excl + h0 + h1 + h2;
  __syncthreads();

  for (int i = t; i < nper; i += 256) {
    int node = node_base + i;
    if (node < N) {
      row_start[node] = b * capb + cur[i];
      degv[node] = hist[i];
    }
  }
  __syncthreads();

  for (int i = t; i < cnt_b; i += 256) {
    int rec = reg[i];
    int pos = atomicAdd(&cur[rec >> 17], 1);
    csr_rows[(size_t)b * capb + pos] = rec & ROWMASK;
  }
}

// ------------- fused: gather-agg + MFMA GEMM + pred + log_softmax -------------

__launch_bounds__(256)
__global__ void fused_node_kernel(const int* __restrict__ csr_rows,
                                  const int* __restrict__ row_start,
                                  const int* __restrict__ degv,
                                  const unsigned short* __restrict__ emb_bf,
                                  const float* __restrict__ feat,
                                  const unsigned short* __restrict__ Wcat,
                                  const unsigned short* __restrict__ Wpb,
                                  const float* __restrict__ bg,
                                  const float* __restrict__ bpred,
                                  float* __restrict__ out, int N) {
  __shared__ __align__(16) unsigned short buf[BM * AS_STRIDE];  // 16896 B
  unsigned short* AsU = buf;
  unsigned short* HsU = buf;                                    // aliased after GEMM1
  float* Lg = (float*)(buf + BM * HS_STRIDE);                   // bytes [8704, 14848)
  int t = threadIdx.x;
  int node0 = blockIdx.x * BM;

  // phase 0: feat -> As[:,128:256) as bf16 (nontemporal: one-touch stream)
  {
    int row = t >> 3, chunk = t & 7;
    int node = node0 + row;
    const f32x4* fp = reinterpret_cast<const f32x4*>(feat + (size_t)node * HID + chunk * 16);
    us8 o0 = {0, 0, 0, 0, 0, 0, 0, 0}, o1 = o0;
    if (node < N) {
      f32x4 f0 = __builtin_nontemporal_load(fp + 0);
      f32x4 f1 = __builtin_nontemporal_load(fp + 1);
      f32x4 f2 = __builtin_nontemporal_load(fp + 2);
      f32x4 f3 = __builtin_nontemporal_load(fp + 3);
      o0[0] = f2bf(f0[0]); o0[1] = f2bf(f0[1]); o0[2] = f2bf(f0[2]); o0[3] = f2bf(f0[3]);
      o0[4] = f2bf(f1[0]); o0[5] = f2bf(f1[1]); o0[6] = f2bf(f1[2]); o0[7] = f2bf(f1[3]);
      o1[0] = f2bf(f2[0]); o1[1] = f2bf(f2[1]); o1[2] = f2bf(f2[2]); o1[3] = f2bf(f2[3]);
      o1[4] = f2bf(f3[0]); o1[5] = f2bf(f3[1]); o1[6] = f2bf(f3[2]); o1[7] = f2bf(f3[3]);
    }
    unsigned short* wp = AsU + row * AS_STRIDE + HID + chunk * 16;
    *reinterpret_cast<us8*>(wp) = o0;
    *reinterpret_cast<us8*>(wp + 8) = o1;
  }

  // phase 1: gather-aggregate — full wave per node, 4 rows per load-instruction,
  // packed f32x2 accumulate (v_pk_add_f32). Group g = lane>>4 takes row i+g.
  int lane = t & 63, wv = t >> 6;
  int g = lane >> 4, l16g = lane & 15;
  for (int nn = wv; nn < BM; nn += 4) {
    int node = node0 + nn;
    f32x2 acc2[4] = {{0.f, 0.f}, {0.f, 0.f}, {0.f, 0.f}, {0.f, 0.f}};
    int cnt = 0;
    if (node < N) {
      cnt = degv[node];
      const int* rows = csr_rows + row_start[node];
      int myrow = (lane < cnt) ? rows[lane] : 0;   // coalesced preload (first 64)
      unsigned coff = (unsigned)(l16g << 4);       // byte offset within row
      int i = 0;
      for (; i + 7 < cnt && i + 7 < 64; i += 8) {
        int rA = __shfl(myrow, i + g);
        int rB = __shfl(myrow, i + 4 + g);
        uint4 uA = *reinterpret_cast<const uint4*>(
            (const char*)emb_bf + (((unsigned)rA << 8) + coff));
        uint4 uB = *reinterpret_cast<const uint4*>(
            (const char*)emb_bf + (((unsigned)rB << 8) + coff));
        acc_pk(acc2[0], uA.x); acc_pk(acc2[1], uA.y);
        acc_pk(acc2[2], uA.z); acc_pk(acc2[3], uA.w);
        acc_pk(acc2[0], uB.x); acc_pk(acc2[1], uB.y);
        acc_pk(acc2[2], uB.z); acc_pk(acc2[3], uB.w);
      }
      for (; i + 3 < cnt; i += 4) {
        int idx = i + g;
        int r = (i + 3 < 64) ? __shfl(myrow, idx & 63) : rows[idx];
        uint4 u = *reinterpret_cast<const uint4*>(
            (const char*)emb_bf + (((unsigned)r << 8) + coff));
        acc_pk(acc2[0], u.x); acc_pk(acc2[1], u.y);
        acc_pk(acc2[2], u.z); acc_pk(acc2[3], u.w);
      }
      int rem = cnt - i;                 // 0..3 tail rows
      if (rem > 0) {
        int idx = i + g;
        int rsh = __shfl(myrow, idx & 63);
        if (g < rem) {
          int r = (idx < 64) ? rsh : rows[idx];
          uint4 u = *reinterpret_cast<const uint4*>(
              (const char*)emb_bf + (((unsigned)r << 8) + coff));
          acc_pk(acc2[0], u.x); acc_pk(acc2[1], u.y);
          acc_pk(acc2[2], u.z); acc_pk(acc2[3], u.w);
        }
      }
    }
#pragma unroll
    for (int k = 0; k < 4; ++k) {
      acc2[k][0] += __shfl_xor(acc2[k][0], 16);
      acc2[k][1] += __shfl_xor(acc2[k][1], 16);
      acc2[k][0] += __shfl_xor(acc2[k][0], 32);
      acc2[k][1] += __shfl_xor(acc2[k][1], 32);
    }
    float inv = 1.0f / fmaxf((float)cnt, 1.0f);
    if (g == 0) {
      us8 o;
#pragma unroll
      for (int k = 0; k < 4; ++k) {
        o[2 * k]     = f2bf(acc2[k][0] * inv);
        o[2 * k + 1] = f2bf(acc2[k][1] * inv);
      }
      *reinterpret_cast<us8*>(AsU + nn * AS_STRIDE + l16g * 8) = o;
    }
  }
  __syncthreads();

  // phase 2: GEMM1 via MFMA 16x16x32 bf16. wave w: colblocks {2w,2w+1}, rowblocks {0,1}
  int w = wv, l16 = lane & 15, quad = lane >> 4;
  f32x4 acc[2][2] = {{{0.f, 0.f, 0.f, 0.f}, {0.f, 0.f, 0.f, 0.f}},
                     {{0.f, 0.f, 0.f, 0.f}, {0.f, 0.f, 0.f, 0.f}}};
#pragma unroll
  for (int kb = 0; kb < 8; ++kb) {
    int ko = kb * 32 + quad * 8;
    bf16x8 a0 = *reinterpret_cast<const bf16x8*>(AsU + l16 * AS_STRIDE + ko);
    bf16x8 a1 = *reinterpret_cast<const bf16x8*>(AsU + (16 + l16) * AS_STRIDE + ko);
    bf16x8 b0 = *reinterpret_cast<const bf16x8*>(Wcat + ((w * 2 + 0) * 16 + l16) * KTOT + ko);
    bf16x8 b1 = *reinterpret_cast<const bf16x8*>(Wcat + ((w * 2 + 1) * 16 + l16) * KTOT + ko);
    acc[0][0] = __builtin_amdgcn_mfma_f32_16x16x32_bf16(a0, b0, acc[0][0], 0, 0, 0);
    acc[0][1] = __builtin_amdgcn_mfma_f32_16x16x32_bf16(a0, b1, acc[0][1], 0, 0, 0);
    acc[1][0] = __builtin_amdgcn_mfma_f32_16x16x32_bf16(a1, b0, acc[1][0], 0, 0, 0);
    acc[1][1] = __builtin_amdgcn_mfma_f32_16x16x32_bf16(a1, b1, acc[1][1], 0, 0, 0);
  }
  __syncthreads();   // all As reads done; buf reusable as Hs

  // bias + relu -> Hs bf16
#pragma unroll
  for (int ci = 0; ci < 2; ++ci) {
    int col = (w * 2 + ci) * 16 + l16;
    float bgv = bg[col];
#pragma unroll
    for (int r = 0; r < 2; ++r)
#pragma unroll
      for (int i = 0; i < 4; ++i) {
        int row = r * 16 + quad * 4 + i;
        float hh = fmaxf(acc[r][ci][i] + bgv, 0.0f);
        HsU[row * HS_STRIDE + col] = f2bf(hh);
      }
  }
  __syncthreads();

  // phase 3: pred head via MFMA (48-col padded), 6 tiles over 4 waves
  for (int tid = w; tid < 6; tid += 4) {
    int r2 = tid & 1, cb = tid >> 1;
    f32x4 acc2p = {0.f, 0.f, 0.f, 0.f};
#pragma unroll
    for (int kb = 0; kb < 4; ++kb) {
      int ko = kb * 32 + quad * 8;
      bf16x8 a = *reinterpret_cast<const bf16x8*>(HsU + (r2 * 16 + l16) * HS_STRIDE + ko);
      bf16x8 b = *reinterpret_cast<const bf16x8*>(Wpb + (cb * 16 + l16) * HID + ko);
      acc2p = __builtin_amdgcn_mfma_f32_16x16x32_bf16(a, b, acc2p, 0, 0, 0);
    }
    int p = cb * 16 + l16;
    if (p < PREDN) {
      float bp = bpred[p];
#pragma unroll
      for (int i = 0; i < 4; ++i)
        Lg[(r2 * 16 + quad * 4 + i) * LG_STRIDE + p] = acc2p[i] + bp;
    }
  }
  __syncthreads();

  // phase 4: log_softmax, half-wave per node (nontemporal out stores)
  int hw = t >> 5, l32 = lane & 31;
  for (int nn = hw; nn < BM; nn += 8) {
    float v0 = Lg[nn * LG_STRIDE + l32];
    float v1 = (l32 < 8) ? Lg[nn * LG_STRIDE + 32 + l32] : -1e30f;
    float m = fmaxf(v0, v1);
    for (int off = 16; off; off >>= 1) m = fmaxf(m, __shfl_xor(m, off, 32));
    float s = expf(v0 - m) + ((l32 < 8) ? expf(v1 - m) : 0.f);
    for (int off = 16; off; off >>= 1) s += __shfl_xor(s, off, 32);
    float lse = m + logf(s);
    int gn = node0 + nn;
    if (gn < N) {
      __builtin_nontemporal_store(v0 - lse, out + (size_t)gn * PREDN + l32);
      if (l32 < 8)
        __builtin_nontemporal_store(v1 - lse, out + (size_t)gn * PREDN + 32 + l32);
    }
  }
}

extern "C" void kernel_launch(void* const* d_in, const int* in_sizes, int n_in,
                              void* d_out, int out_size, void* d_ws, size_t ws_size,
                              hipStream_t stream) {
  const int*   node_index = (const int*)d_in[0];
  const float* node_feat  = (const float*)d_in[1];
  const int*   edge_index = (const int*)d_in[2];
  const float* emb        = (const float*)d_in[3];
  const float* Wmsg       = (const float*)d_in[4];
  const float* Wnode      = (const float*)d_in[5];
  const float* bg         = (const float*)d_in[6];
  const float* Wpred      = (const float*)d_in[7];
  const float* bpred      = (const float*)d_in[8];

  const int N = in_sizes[0];          // 100000
  const int E = in_sizes[2] / 2;      // 1600000

  const int nbucket = (N + (1 << BSHIFT) - 1) >> BSHIFT;       // 98 (<=128)
  int capb = E / nbucket + E / (4 * nbucket) + 2048;           // mean + 25% + slack
  capb = (capb + 15) & ~15;                                    // line-align (16 recs = 64B)

  int* gcur      = (int*)d_ws;                                 // nbucket*CUR_STRIDE
  int* region    = gcur + (size_t)nbucket * CUR_STRIDE;        // nbucket*capb (packed recs)
  int* csr_rows  = region + (size_t)nbucket * capb;            // nbucket*capb
  int* row_start = csr_rows + (size_t)nbucket * capb;          // N
  int* degv      = row_start + N;                              // N
  size_t off = (((size_t)(degv + N) - (size_t)d_ws) + 15) & ~(size_t)15;
  unsigned short* emb_bf = (unsigned short*)((char*)d_ws + off); // N*128
  unsigned short* Wcat   = emb_bf + (size_t)N * HID;             // 128*256
  unsigned short* Wpb    = Wcat + 128 * 256;                     // 48*128

  hipMemsetAsync(gcur, 0, (size_t)nbucket * CUR_STRIDE * sizeof(int), stream);

  const int ntile = (E + 256 * EPT - 1) / (256 * EPT);   // 391
  const int nconv = 416;
  const int nw    = 64;
  prologue_kernel<<<ntile + nconv + nw, 256, 0, stream>>>(
      edge_index, node_index, emb, Wmsg, Wnode, Wpred,
      gcur, region, emb_bf, Wcat, Wpb,
      E, N, nbucket, capb, ntile, nconv, nw);

  refine_kernel<<<nbucket, 256, 0, stream>>>(region, gcur, csr_rows,
                                             row_start, degv, N, capb);

  int nblk = (N + BM - 1) / BM;
  fused_node_kernel<<<nblk, 256, 0, stream>>>(csr_rows, row_start, degv,
                                              emb_bf, node_feat, Wcat, Wpb,
                                              bg, bpred, (float*)d_out, N);
}

// Round 12
// 168.546 us; speedup vs baseline: 1.0799x; 1.0148x over previous
//
#include <hip/hip_runtime.h>
#include <math.h>

#define HID   128
#define KTOT  256
#define PREDN 40
#define BM    32
#define AS_STRIDE 264   // ushorts: 256 + 8 pad; 528B rows keep 16B align
#define HS_STRIDE 136   // 128 + 8 pad
#define LG_STRIDE 48
#define CUR_STRIDE 16   // ints: one 64B line per bucket counter
#define EPT   16        // edges per thread in bin branch
#define BSHIFT 10       // 1024 nodes per coarse bucket
#define ROWMASK 0x1FFFF // low 17 bits = emb row (N < 131072)

typedef __attribute__((ext_vector_type(8))) short bf16x8;
typedef __attribute__((ext_vector_type(4))) float f32x4;
typedef __attribute__((ext_vector_type(2))) float f32x2;
typedef __attribute__((ext_vector_type(4))) unsigned short us4;
typedef __attribute__((ext_vector_type(8))) unsigned short us8;

__device__ __forceinline__ unsigned short f2bf(float f) {
  unsigned int u = __float_as_uint(f);
  u = (u + 0x7FFFu + ((u >> 16) & 1u)) >> 16;   // round-to-nearest-even
  return (unsigned short)u;
}
__device__ __forceinline__ float bf2f(unsigned short b) {
  return __uint_as_float(((unsigned int)b) << 16);
}

// accumulate 2 bf16 (packed in one uint) into an f32 pair with one v_pk_add_f32
__device__ __forceinline__ void acc_pk(f32x2& acc, unsigned int u) {
  f32x2 val;
  val[0] = __uint_as_float(u << 16);
  val[1] = __uint_as_float(u & 0xffff0000u);
  asm("v_pk_add_f32 %0, %0, %1" : "+v"(acc) : "v"(val));
}

// ------------- fused prologue: bin edges | emb->bf16 | weights->bf16 -------------

__global__ void prologue_kernel(const int* __restrict__ ei,
                                const int* __restrict__ nidx,
                                const float* __restrict__ emb,
                                const float* __restrict__ Wmsg,
                                const float* __restrict__ Wnode,
                                const float* __restrict__ Wpred,
                                int* __restrict__ gcur,
                                int* __restrict__ region,
                                unsigned short* __restrict__ emb_bf,
                                unsigned short* __restrict__ Wcat,
                                unsigned short* __restrict__ Wpb,
                                int E, int N, int nbucket, int capb,
                                int ntile, int nconv, int nw) {
  int b = blockIdx.x;
  int t = threadIdx.x;
  if (b < ntile) {
    // --- bin: records packed (local_dst<<17)|row, chunked per WG for full-line
    //     writes. Scalar strided loads (R8 form — measured fastest).
    __shared__ int hist[128];
    __shared__ int base[128];
    int tb = b * (256 * EPT);
    if (t < 128) hist[t] = 0;
    __syncthreads();
    int rec[EPT], bk[EPT];
#pragma unroll
    for (int j = 0; j < EPT; ++j) {
      int idx = tb + j * 256 + t;
      if (idx < E) {
        int d = ei[E + idx];
        int r = nidx[ei[idx]];
        bk[j] = d >> BSHIFT;
        rec[j] = ((d & ((1 << BSHIFT) - 1)) << 17) | r;
        atomicAdd(&hist[bk[j]], 1);
      } else {
        bk[j] = -1;
      }
    }
    __syncthreads();
    if (t < nbucket && hist[t] > 0) base[t] = atomicAdd(&gcur[t * CUR_STRIDE], hist[t]);
    __syncthreads();
    if (t < 128) hist[t] = 0;     // reuse as intra-chunk cursor
    __syncthreads();
#pragma unroll
    for (int j = 0; j < EPT; ++j) {
      if (bk[j] >= 0) {
        int pos = base[bk[j]] + atomicAdd(&hist[bk[j]], 1);
        if (pos < capb) region[(size_t)bk[j] * capb + pos] = rec[j];
      }
    }
  } else if (b < ntile + nconv) {
    // --- emb fp32 -> bf16 (plain loads)
    int i = (b - ntile) * 256 + t;
    int stride = nconv * 256;
    int total4 = N * (HID / 4);
    for (; i < total4; i += stride) {
      float4 v = reinterpret_cast<const float4*>(emb)[i];
      us4 o;
      o.x = f2bf(v.x); o.y = f2bf(v.y); o.z = f2bf(v.z); o.w = f2bf(v.w);
      reinterpret_cast<us4*>(emb_bf)[i] = o;
    }
  } else {
    // --- weights -> bf16 (Wcat = [Wmsg|Wnode] K-major, Wpb = Wpred padded to 48)
    int i = (b - ntile - nconv) * 256 + t;
    int stride = nw * 256;
    for (; i < 128 * 256 + 48 * 128; i += stride) {
      if (i < 128 * 256) {
        int j = i >> 8, k = i & 255;
        float v = (k < HID) ? Wmsg[j * HID + k] : Wnode[j * HID + (k - HID)];
        Wcat[i] = f2bf(v);
      } else {
        int u = i - 128 * 256;
        int p = u >> 7, k = u & 127;
        Wpb[u] = (p < PREDN) ? f2bf(Wpred[p * HID + k]) : (unsigned short)0;
      }
    }
  }
}

// ------------- refine: coarse bucket -> compact per-node CSR (one WG/bucket) -------------

__global__ void refine_kernel(const int* __restrict__ region,
                              const int* __restrict__ gcur,
                              int* __restrict__ csr_rows,
                              int* __restrict__ row_start,
                              int* __restrict__ degv,
                              int N, int capb) {
  __shared__ int hist[1 << BSHIFT];
  __shared__ int cur[1 << BSHIFT];
  __shared__ int ts[256];
  int b = blockIdx.x, t = threadIdx.x;
  int node_base = b << BSHIFT;
  const int nper = 1 << BSHIFT;
  int cnt_b = gcur[b * CUR_STRIDE];
  if (cnt_b > capb) cnt_b = capb;
  const int* reg = region + (size_t)b * capb;

  for (int i = t; i < nper; i += 256) hist[i] = 0;
  __syncthreads();
  for (int i = t; i < cnt_b; i += 256)
    atomicAdd(&hist[reg[i] >> 17], 1);
  __syncthreads();

  int h0 = hist[t * 4], h1 = hist[t * 4 + 1], h2 = hist[t * 4 + 2], h3 = hist[t * 4 + 3];
  int tsum = h0 + h1 + h2 + h3;
  ts[t] = tsum;
  __syncthreads();
  int v = tsum;
  for (int off = 1; off < 256; off <<= 1) {
    int o = (t >= off) ? ts[t - off] : 0;
    __syncthreads();
    v += o;
    ts[t] = v;
    __syncthreads();
  }
  int excl = v - tsum;
  cur[t * 4 + 0] = excl;
  cur[t * 4 + 1] = excl + h0;
  cur[t * 4 + 2] = excl + h0 + h1;
  cur[t * 4 + 3] = excl + h0 + h1 + h2;
  __syncthreads();

  for (int i = t; i < nper; i += 256) {
    int node = node_base + i;
    if (node < N) {
      row_start[node] = b * capb + cur[i];
      degv[node] = hist[i];
    }
  }
  __syncthreads();

  for (int i = t; i < cnt_b; i += 256) {
    int rec = reg[i];
    int pos = atomicAdd(&cur[rec >> 17], 1);
    csr_rows[(size_t)b * capb + pos] = rec & ROWMASK;
  }
}

// ------------- fused: gather-agg + MFMA GEMM + pred + log_softmax -------------

__launch_bounds__(256)
__global__ void fused_node_kernel(const int* __restrict__ csr_rows,
                                  const int* __restrict__ row_start,
                                  const int* __restrict__ degv,
                                  const unsigned short* __restrict__ emb_bf,
                                  const float* __restrict__ feat,
                                  const unsigned short* __restrict__ Wcat,
                                  const unsigned short* __restrict__ Wpb,
                                  const float* __restrict__ bg,
                                  const float* __restrict__ bpred,
                                  float* __restrict__ out, int N) {
  __shared__ __align__(16) unsigned short buf[BM * AS_STRIDE];  // 16896 B
  unsigned short* AsU = buf;
  unsigned short* HsU = buf;                                    // aliased after GEMM1
  float* Lg = (float*)(buf + BM * HS_STRIDE);                   // bytes [8704, 14848)
  int t = threadIdx.x;
  int node0 = blockIdx.x * BM;

  // phase 0: feat -> As[:,128:256) as bf16 (nontemporal: one-touch stream)
  {
    int row = t >> 3, chunk = t & 7;
    int node = node0 + row;
    const f32x4* fp = reinterpret_cast<const f32x4*>(feat + (size_t)node * HID + chunk * 16);
    us8 o0 = {0, 0, 0, 0, 0, 0, 0, 0}, o1 = o0;
    if (node < N) {
      f32x4 f0 = __builtin_nontemporal_load(fp + 0);
      f32x4 f1 = __builtin_nontemporal_load(fp + 1);
      f32x4 f2 = __builtin_nontemporal_load(fp + 2);
      f32x4 f3 = __builtin_nontemporal_load(fp + 3);
      o0[0] = f2bf(f0[0]); o0[1] = f2bf(f0[1]); o0[2] = f2bf(f0[2]); o0[3] = f2bf(f0[3]);
      o0[4] = f2bf(f1[0]); o0[5] = f2bf(f1[1]); o0[6] = f2bf(f1[2]); o0[7] = f2bf(f1[3]);
      o1[0] = f2bf(f2[0]); o1[1] = f2bf(f2[1]); o1[2] = f2bf(f2[2]); o1[3] = f2bf(f2[3]);
      o1[4] = f2bf(f3[0]); o1[5] = f2bf(f3[1]); o1[6] = f2bf(f3[2]); o1[7] = f2bf(f3[3]);
    }
    unsigned short* wp = AsU + row * AS_STRIDE + HID + chunk * 16;
    *reinterpret_cast<us8*>(wp) = o0;
    *reinterpret_cast<us8*>(wp + 8) = o1;
  }

  // phase 1: gather-aggregate — full wave per node, 4 rows per load-instruction,
  // packed f32x2 accumulate (v_pk_add_f32). Group g = lane>>4 takes row i+g.
  int lane = t & 63, wv = t >> 6;
  int g = lane >> 4, l16g = lane & 15;
  for (int nn = wv; nn < BM; nn += 4) {
    int node = node0 + nn;
    f32x2 acc2[4] = {{0.f, 0.f}, {0.f, 0.f}, {0.f, 0.f}, {0.f, 0.f}};
    int cnt = 0;
    if (node < N) {
      cnt = degv[node];
      const int* rows = csr_rows + row_start[node];
      int myrow = (lane < cnt) ? rows[lane] : 0;   // coalesced preload (first 64)
      unsigned coff = (unsigned)(l16g << 4);       // byte offset within row
      int i = 0;
      for (; i + 7 < cnt && i + 7 < 64; i += 8) {
        int rA = __shfl(myrow, i + g);
        int rB = __shfl(myrow, i + 4 + g);
        uint4 uA = *reinterpret_cast<const uint4*>(
            (const char*)emb_bf + (((unsigned)rA << 8) + coff));
        uint4 uB = *reinterpret_cast<const uint4*>(
            (const char*)emb_bf + (((unsigned)rB << 8) + coff));
        acc_pk(acc2[0], uA.x); acc_pk(acc2[1], uA.y);
        acc_pk(acc2[2], uA.z); acc_pk(acc2[3], uA.w);
        acc_pk(acc2[0], uB.x); acc_pk(acc2[1], uB.y);
        acc_pk(acc2[2], uB.z); acc_pk(acc2[3], uB.w);
      }
      for (; i + 3 < cnt; i += 4) {
        int idx = i + g;
        int r = (i + 3 < 64) ? __shfl(myrow, idx & 63) : rows[idx];
        uint4 u = *reinterpret_cast<const uint4*>(
            (const char*)emb_bf + (((unsigned)r << 8) + coff));
        acc_pk(acc2[0], u.x); acc_pk(acc2[1], u.y);
        acc_pk(acc2[2], u.z); acc_pk(acc2[3], u.w);
      }
      int rem = cnt - i;                 // 0..3 tail rows
      if (rem > 0) {
        int idx = i + g;
        int rsh = __shfl(myrow, idx & 63);
        if (g < rem) {
          int r = (idx < 64) ? rsh : rows[idx];
          uint4 u = *reinterpret_cast<const uint4*>(
              (const char*)emb_bf + (((unsigned)r << 8) + coff));
          acc_pk(acc2[0], u.x); acc_pk(acc2[1], u.y);
          acc_pk(acc2[2], u.z); acc_pk(acc2[3], u.w);
        }
      }
    }
#pragma unroll
    for (int k = 0; k < 4; ++k) {
      acc2[k][0] += __shfl_xor(acc2[k][0], 16);
      acc2[k][1] += __shfl_xor(acc2[k][1], 16);
      acc2[k][0] += __shfl_xor(acc2[k][0], 32);
      acc2[k][1] += __shfl_xor(acc2[k][1], 32);
    }
    float inv = 1.0f / fmaxf((float)cnt, 1.0f);
    if (g == 0) {
      us8 o;
#pragma unroll
      for (int k = 0; k < 4; ++k) {
        o[2 * k]     = f2bf(acc2[k][0] * inv);
        o[2 * k + 1] = f2bf(acc2[k][1] * inv);
      }
      *reinterpret_cast<us8*>(AsU + nn * AS_STRIDE + l16g * 8) = o;
    }
  }
  __syncthreads();

  // phase 2: GEMM1 via MFMA 16x16x32 bf16. wave w: colblocks {2w,2w+1}, rowblocks {0,1}
  int w = wv, l16 = lane & 15, quad = lane >> 4;
  f32x4 acc[2][2] = {{{0.f, 0.f, 0.f, 0.f}, {0.f, 0.f, 0.f, 0.f}},
                     {{0.f, 0.f, 0.f, 0.f}, {0.f, 0.f, 0.f, 0.f}}};
#pragma unroll
  for (int kb = 0; kb < 8; ++kb) {
    int ko = kb * 32 + quad * 8;
    bf16x8 a0 = *reinterpret_cast<const bf16x8*>(AsU + l16 * AS_STRIDE + ko);
    bf16x8 a1 = *reinterpret_cast<const bf16x8*>(AsU + (16 + l16) * AS_STRIDE + ko);
    bf16x8 b0 = *reinterpret_cast<const bf16x8*>(Wcat + ((w * 2 + 0) * 16 + l16) * KTOT + ko);
    bf16x8 b1 = *reinterpret_cast<const bf16x8*>(Wcat + ((w * 2 + 1) * 16 + l16) * KTOT + ko);
    acc[0][0] = __builtin_amdgcn_mfma_f32_16x16x32_bf16(a0, b0, acc[0][0], 0, 0, 0);
    acc[0][1] = __builtin_amdgcn_mfma_f32_16x16x32_bf16(a0, b1, acc[0][1], 0, 0, 0);
    acc[1][0] = __builtin_amdgcn_mfma_f32_16x16x32_bf16(a1, b0, acc[1][0], 0, 0, 0);
    acc[1][1] = __builtin_amdgcn_mfma_f32_16x16x32_bf16(a1, b1, acc[1][1], 0, 0, 0);
  }
  __syncthreads();   // all As reads done; buf reusable as Hs

  // bias + relu -> Hs bf16
#pragma unroll
  for (int ci = 0; ci < 2; ++ci) {
    int col = (w * 2 + ci) * 16 + l16;
    float bgv = bg[col];
#pragma unroll
    for (int r = 0; r < 2; ++r)
#pragma unroll
      for (int i = 0; i < 4; ++i) {
        int row = r * 16 + quad * 4 + i;
        float hh = fmaxf(acc[r][ci][i] + bgv, 0.0f);
        HsU[row * HS_STRIDE + col] = f2bf(hh);
      }
  }
  __syncthreads();

  // phase 3: pred head via MFMA (48-col padded), 6 tiles over 4 waves
  for (int tid = w; tid < 6; tid += 4) {
    int r2 = tid & 1, cb = tid >> 1;
    f32x4 acc2p = {0.f, 0.f, 0.f, 0.f};
#pragma unroll
    for (int kb = 0; kb < 4; ++kb) {
      int ko = kb * 32 + quad * 8;
      bf16x8 a = *reinterpret_cast<const bf16x8*>(HsU + (r2 * 16 + l16) * HS_STRIDE + ko);
      bf16x8 b = *reinterpret_cast<const bf16x8*>(Wpb + (cb * 16 + l16) * HID + ko);
      acc2p = __builtin_amdgcn_mfma_f32_16x16x32_bf16(a, b, acc2p, 0, 0, 0);
    }
    int p = cb * 16 + l16;
    if (p < PREDN) {
      float bp = bpred[p];
#pragma unroll
      for (int i = 0; i < 4; ++i)
        Lg[(r2 * 16 + quad * 4 + i) * LG_STRIDE + p] = acc2p[i] + bp;
    }
  }
  __syncthreads();

  // phase 4: log_softmax, half-wave per node (nontemporal out stores)
  int hw = t >> 5, l32 = lane & 31;
  for (int nn = hw; nn < BM; nn += 8) {
    float v0 = Lg[nn * LG_STRIDE + l32];
    float v1 = (l32 < 8) ? Lg[nn * LG_STRIDE + 32 + l32] : -1e30f;
    float m = fmaxf(v0, v1);
    for (int off = 16; off; off >>= 1) m = fmaxf(m, __shfl_xor(m, off, 32));
    float s = expf(v0 - m) + ((l32 < 8) ? expf(v1 - m) : 0.f);
    for (int off = 16; off; off >>= 1) s += __shfl_xor(s, off, 32);
    float lse = m + logf(s);
    int gn = node0 + nn;
    if (gn < N) {
      __builtin_nontemporal_store(v0 - lse, out + (size_t)gn * PREDN + l32);
      if (l32 < 8)
        __builtin_nontemporal_store(v1 - lse, out + (size_t)gn * PREDN + 32 + l32);
    }
  }
}

extern "C" void kernel_launch(void* const* d_in, const int* in_sizes, int n_in,
                              void* d_out, int out_size, void* d_ws, size_t ws_size,
                              hipStream_t stream) {
  const int*   node_index = (const int*)d_in[0];
  const float* node_feat  = (const float*)d_in[1];
  const int*   edge_index = (const int*)d_in[2];
  const float* emb        = (const float*)d_in[3];
  const float* Wmsg       = (const float*)d_in[4];
  const float* Wnode      = (const float*)d_in[5];
  const float* bg         = (const float*)d_in[6];
  const float* Wpred      = (const float*)d_in[7];
  const float* bpred      = (const float*)d_in[8];

  const int N = in_sizes[0];          // 100000
  const int E = in_sizes[2] / 2;      // 1600000

  const int nbucket = (N + (1 << BSHIFT) - 1) >> BSHIFT;       // 98 (<=128)
  int capb = E / nbucket + E / (4 * nbucket) + 2048;           // mean + 25% + slack
  capb = (capb + 15) & ~15;                                    // line-align (16 recs = 64B)

  int* gcur      = (int*)d_ws;                                 // nbucket*CUR_STRIDE
  int* region    = gcur + (size_t)nbucket * CUR_STRIDE;        // nbucket*capb (packed recs)
  int* csr_rows  = region + (size_t)nbucket * capb;            // nbucket*capb
  int* row_start = csr_rows + (size_t)nbucket * capb;          // N
  int* degv      = row_start + N;                              // N
  size_t off = (((size_t)(degv + N) - (size_t)d_ws) + 15) & ~(size_t)15;
  unsigned short* emb_bf = (unsigned short*)((char*)d_ws + off); // N*128
  unsigned short* Wcat   = emb_bf + (size_t)N * HID;             // 128*256
  unsigned short* Wpb    = Wcat + 128 * 256;                     // 48*128

  hipMemsetAsync(gcur, 0, (size_t)nbucket * CUR_STRIDE * sizeof(int), stream);

  const int ntile = (E + 256 * EPT - 1) / (256 * EPT);   // 391
  const int nconv = 416;
  const int nw    = 64;
  prologue_kernel<<<ntile + nconv + nw, 256, 0, stream>>>(
      edge_index, node_index, emb, Wmsg, Wnode, Wpred,
      gcur, region, emb_bf, Wcat, Wpb,
      E, N, nbucket, capb, ntile, nconv, nw);

  refine_kernel<<<nbucket, 256, 0, stream>>>(region, gcur, csr_rows,
                                             row_start, degv, N, capb);

  int nblk = (N + BM - 1) / BM;
  fused_node_kernel<<<nblk, 256, 0, stream>>>(csr_rows, row_start, degv,
                                              emb_bf, node_feat, Wcat, Wpb,
                                              bg, bpred, (float*)d_out, N);
}

// Round 13
// 163.866 us; speedup vs baseline: 1.1107x; 1.0286x over previous
//
#include <hip/hip_runtime.h>
#include <math.h>

#define HID   128
#define KTOT  256
#define PREDN 40
#define BM    32
#define AS_STRIDE 264   // ushorts: 256 + 8 pad; 528B rows keep 16B align
#define HS_STRIDE 136   // 128 + 8 pad
#define LG_STRIDE 48
#define CUR_STRIDE 16   // ints: one 64B line per bucket counter
#define EPT   16        // edges per thread in bin branch
#define BSHIFT 10       // 1024 nodes per coarse bucket
#define ROWMASK 0x1FFFF // low 17 bits = emb row (N < 131072)

typedef __attribute__((ext_vector_type(8))) short bf16x8;
typedef __attribute__((ext_vector_type(4))) float f32x4;
typedef __attribute__((ext_vector_type(4))) unsigned short us4;
typedef __attribute__((ext_vector_type(8))) unsigned short us8;

__device__ __forceinline__ unsigned short f2bf(float f) {
  unsigned int u = __float_as_uint(f);
  u = (u + 0x7FFFu + ((u >> 16) & 1u)) >> 16;   // round-to-nearest-even
  return (unsigned short)u;
}
__device__ __forceinline__ float bf2f(unsigned short b) {
  return __uint_as_float(((unsigned int)b) << 16);
}

// ------------- fused prologue: bin edges | emb->bf16 | weights->bf16 -------------

__global__ void prologue_kernel(const int* __restrict__ ei,
                                const int* __restrict__ nidx,
                                const float* __restrict__ emb,
                                const float* __restrict__ Wmsg,
                                const float* __restrict__ Wnode,
                                const float* __restrict__ Wpred,
                                int* __restrict__ gcur,
                                int* __restrict__ region,
                                unsigned short* __restrict__ emb_bf,
                                unsigned short* __restrict__ Wcat,
                                unsigned short* __restrict__ Wpb,
                                int E, int N, int nbucket, int capb,
                                int ntile, int nconv, int nw) {
  int b = blockIdx.x;
  int t = threadIdx.x;
  if (b < ntile) {
    // --- bin: records packed (local_dst<<17)|row, chunked per WG for full-line writes
    __shared__ int hist[128];
    __shared__ int base[128];
    int tb = b * (256 * EPT);
    if (t < 128) hist[t] = 0;
    __syncthreads();
    int rec[EPT], bk[EPT];
#pragma unroll
    for (int j = 0; j < EPT; ++j) {
      int idx = tb + j * 256 + t;
      if (idx < E) {
        int d = ei[E + idx];
        int r = nidx[ei[idx]];
        bk[j] = d >> BSHIFT;
        rec[j] = ((d & ((1 << BSHIFT) - 1)) << 17) | r;
        atomicAdd(&hist[bk[j]], 1);
      } else {
        bk[j] = -1;
      }
    }
    __syncthreads();
    if (t < nbucket && hist[t] > 0) base[t] = atomicAdd(&gcur[t * CUR_STRIDE], hist[t]);
    __syncthreads();
    if (t < 128) hist[t] = 0;     // reuse as intra-chunk cursor
    __syncthreads();
#pragma unroll
    for (int j = 0; j < EPT; ++j) {
      if (bk[j] >= 0) {
        int pos = base[bk[j]] + atomicAdd(&hist[bk[j]], 1);
        if (pos < capb) region[(size_t)bk[j] * capb + pos] = rec[j];
      }
    }
  } else if (b < ntile + nconv) {
    // --- emb fp32 -> bf16
    int i = (b - ntile) * 256 + t;
    int stride = nconv * 256;
    int total4 = N * (HID / 4);
    for (; i < total4; i += stride) {
      float4 v = reinterpret_cast<const float4*>(emb)[i];
      us4 o;
      o.x = f2bf(v.x); o.y = f2bf(v.y); o.z = f2bf(v.z); o.w = f2bf(v.w);
      reinterpret_cast<us4*>(emb_bf)[i] = o;
    }
  } else {
    // --- weights -> bf16 (Wcat = [Wmsg|Wnode] K-major, Wpb = Wpred padded to 48)
    int i = (b - ntile - nconv) * 256 + t;
    int stride = nw * 256;
    for (; i < 128 * 256 + 48 * 128; i += stride) {
      if (i < 128 * 256) {
        int j = i >> 8, k = i & 255;
        float v = (k < HID) ? Wmsg[j * HID + k] : Wnode[j * HID + (k - HID)];
        Wcat[i] = f2bf(v);
      } else {
        int u = i - 128 * 256;
        int p = u >> 7, k = u & 127;
        Wpb[u] = (p < PREDN) ? f2bf(Wpred[p * HID + k]) : (unsigned short)0;
      }
    }
  }
}

// ------------- refine: coarse bucket -> compact per-node CSR (one WG/bucket) -------------

__global__ void refine_kernel(const int* __restrict__ region,
                              const int* __restrict__ gcur,
                              int* __restrict__ csr_rows,
                              int* __restrict__ row_start,
                              int* __restrict__ degv,
                              int N, int capb) {
  __shared__ int hist[1 << BSHIFT];
  __shared__ int cur[1 << BSHIFT];
  __shared__ int ts[256];
  int b = blockIdx.x, t = threadIdx.x;
  int node_base = b << BSHIFT;
  const int nper = 1 << BSHIFT;
  int cnt_b = gcur[b * CUR_STRIDE];
  if (cnt_b > capb) cnt_b = capb;
  const int* reg = region + (size_t)b * capb;

  for (int i = t; i < nper; i += 256) hist[i] = 0;
  __syncthreads();
  for (int i = t; i < cnt_b; i += 256)
    atomicAdd(&hist[reg[i] >> 17], 1);
  __syncthreads();

  int h0 = hist[t * 4], h1 = hist[t * 4 + 1], h2 = hist[t * 4 + 2], h3 = hist[t * 4 + 3];
  int tsum = h0 + h1 + h2 + h3;
  ts[t] = tsum;
  __syncthreads();
  int v = tsum;
  for (int off = 1; off < 256; off <<= 1) {
    int o = (t >= off) ? ts[t - off] : 0;
    __syncthreads();
    v += o;
    ts[t] = v;
    __syncthreads();
  }
  int excl = v - tsum;
  cur[t * 4 + 0] = excl;
  cur[t * 4 + 1] = excl + h0;
  cur[t * 4 + 2] = excl + h0 + h1;
  cur[t * 4 + 3] = excl + h0 + h1 + h2;
  __syncthreads();

  for (int i = t; i < nper; i += 256) {
    int node = node_base + i;
    if (node < N) {
      row_start[node] = b * capb + cur[i];
      degv[node] = hist[i];
    }
  }
  __syncthreads();

  for (int i = t; i < cnt_b; i += 256) {
    int rec = reg[i];
    int pos = atomicAdd(&cur[rec >> 17], 1);
    csr_rows[(size_t)b * capb + pos] = rec & ROWMASK;
  }
}

// ------------- fused: gather-agg + MFMA GEMM + pred + log_softmax -------------

__launch_bounds__(256)
__global__ void fused_node_kernel(const int* __restrict__ csr_rows,
                                  const int* __restrict__ row_start,
                                  const int* __restrict__ degv,
                                  const unsigned short* __restrict__ emb_bf,
                                  const float* __restrict__ feat,
                                  const unsigned short* __restrict__ Wcat,
                                  const unsigned short* __restrict__ Wpb,
                                  const float* __restrict__ bg,
                                  const float* __restrict__ bpred,
                                  float* __restrict__ out, int N) {
  __shared__ __align__(16) unsigned short buf[BM * AS_STRIDE];  // 16896 B
  unsigned short* AsU = buf;
  unsigned short* HsU = buf;                                    // aliased after GEMM1
  float* Lg = (float*)(buf + BM * HS_STRIDE);                   // bytes [8704, 14848)
  int t = threadIdx.x;
  int node0 = blockIdx.x * BM;

  // phase 0: feat -> As[:,128:256) as bf16 (row = t>>3, 16-col chunk = t&7)
  {
    int row = t >> 3, chunk = t & 7;
    int node = node0 + row;
    const float* fp = feat + (size_t)node * HID + chunk * 16;
    us8 o0 = {0, 0, 0, 0, 0, 0, 0, 0}, o1 = o0;
    if (node < N) {
      float4 f0 = reinterpret_cast<const float4*>(fp)[0];
      float4 f1 = reinterpret_cast<const float4*>(fp)[1];
      float4 f2 = reinterpret_cast<const float4*>(fp)[2];
      float4 f3 = reinterpret_cast<const float4*>(fp)[3];
      o0[0] = f2bf(f0.x); o0[1] = f2bf(f0.y); o0[2] = f2bf(f0.z); o0[3] = f2bf(f0.w);
      o0[4] = f2bf(f1.x); o0[5] = f2bf(f1.y); o0[6] = f2bf(f1.z); o0[7] = f2bf(f1.w);
      o1[0] = f2bf(f2.x); o1[1] = f2bf(f2.y); o1[2] = f2bf(f2.z); o1[3] = f2bf(f2.w);
      o1[4] = f2bf(f3.x); o1[5] = f2bf(f3.y); o1[6] = f2bf(f3.z); o1[7] = f2bf(f3.w);
    }
    unsigned short* wp = AsU + row * AS_STRIDE + HID + chunk * 16;
    *reinterpret_cast<us8*>(wp) = o0;
    *reinterpret_cast<us8*>(wp + 8) = o1;
  }

  // phase 1: gather-aggregate — full wave per node, 4 rows per load-instruction.
  // Lane group g = lane>>4 (16 lanes) takes row i+g; each lane loads us8 (16B):
  // one wave-inst = 4 rows = 1KB. Cross-group reduce via 2 shfl_xor at the end.
  int lane = t & 63, wv = t >> 6;
  int g = lane >> 4, l16g = lane & 15;
  for (int nn = wv; nn < BM; nn += 4) {
    int node = node0 + nn;
    float a[8] = {0.f, 0.f, 0.f, 0.f, 0.f, 0.f, 0.f, 0.f};
    int cnt = 0;
    if (node < N) {
      cnt = degv[node];
      const int* rows = csr_rows + row_start[node];
      int myrow = (lane < cnt) ? rows[lane] : 0;   // coalesced preload (first 64)
      int i = 0;
      // 8 rows per pass (2 wave-insts in flight), ids from registers
      for (; i + 7 < cnt && i + 7 < 64; i += 8) {
        int rA = __shfl(myrow, i + g);
        int rB = __shfl(myrow, i + 4 + g);
        us8 vA = *reinterpret_cast<const us8*>(emb_bf + (size_t)rA * HID + l16g * 8);
        us8 vB = *reinterpret_cast<const us8*>(emb_bf + (size_t)rB * HID + l16g * 8);
#pragma unroll
        for (int k = 0; k < 8; ++k) a[k] += bf2f(vA[k]);
#pragma unroll
        for (int k = 0; k < 8; ++k) a[k] += bf2f(vB[k]);
      }
      for (; i + 3 < cnt; i += 4) {
        int idx = i + g;
        int r = (i + 3 < 64) ? __shfl(myrow, idx & 63) : rows[idx];
        us8 v = *reinterpret_cast<const us8*>(emb_bf + (size_t)r * HID + l16g * 8);
#pragma unroll
        for (int k = 0; k < 8; ++k) a[k] += bf2f(v[k]);
      }
      int rem = cnt - i;                 // 0..3 tail rows
      if (rem > 0) {
        int idx = i + g;
        int rsh = __shfl(myrow, idx & 63);
        if (g < rem) {
          int r = (idx < 64) ? rsh : rows[idx];
          us8 v = *reinterpret_cast<const us8*>(emb_bf + (size_t)r * HID + l16g * 8);
#pragma unroll
          for (int k = 0; k < 8; ++k) a[k] += bf2f(v[k]);
        }
      }
    }
#pragma unroll
    for (int k = 0; k < 8; ++k) {
      a[k] += __shfl_xor(a[k], 16);
      a[k] += __shfl_xor(a[k], 32);
    }
    float inv = 1.0f / fmaxf((float)cnt, 1.0f);
    if (g == 0) {
      us8 o;
#pragma unroll
      for (int k = 0; k < 8; ++k) o[k] = f2bf(a[k] * inv);
      *reinterpret_cast<us8*>(AsU + nn * AS_STRIDE + l16g * 8) = o;
    }
  }
  __syncthreads();

  // phase 2: GEMM1 via MFMA 16x16x32 bf16. wave w: colblocks {2w,2w+1}, rowblocks {0,1}
  int w = wv, l16 = lane & 15, quad = lane >> 4;
  f32x4 acc[2][2] = {{{0.f, 0.f, 0.f, 0.f}, {0.f, 0.f, 0.f, 0.f}},
                     {{0.f, 0.f, 0.f, 0.f}, {0.f, 0.f, 0.f, 0.f}}};
#pragma unroll
  for (int kb = 0; kb < 8; ++kb) {
    int ko = kb * 32 + quad * 8;
    bf16x8 a0 = *reinterpret_cast<const bf16x8*>(AsU + l16 * AS_STRIDE + ko);
    bf16x8 a1 = *reinterpret_cast<const bf16x8*>(AsU + (16 + l16) * AS_STRIDE + ko);
    bf16x8 b0 = *reinterpret_cast<const bf16x8*>(Wcat + ((w * 2 + 0) * 16 + l16) * KTOT + ko);
    bf16x8 b1 = *reinterpret_cast<const bf16x8*>(Wcat + ((w * 2 + 1) * 16 + l16) * KTOT + ko);
    acc[0][0] = __builtin_amdgcn_mfma_f32_16x16x32_bf16(a0, b0, acc[0][0], 0, 0, 0);
    acc[0][1] = __builtin_amdgcn_mfma_f32_16x16x32_bf16(a0, b1, acc[0][1], 0, 0, 0);
    acc[1][0] = __builtin_amdgcn_mfma_f32_16x16x32_bf16(a1, b0, acc[1][0], 0, 0, 0);
    acc[1][1] = __builtin_amdgcn_mfma_f32_16x16x32_bf16(a1, b1, acc[1][1], 0, 0, 0);
  }
  __syncthreads();   // all As reads done; buf reusable as Hs

  // bias + relu -> Hs bf16
#pragma unroll
  for (int ci = 0; ci < 2; ++ci) {
    int col = (w * 2 + ci) * 16 + l16;
    float bgv = bg[col];
#pragma unroll
    for (int r = 0; r < 2; ++r)
#pragma unroll
      for (int i = 0; i < 4; ++i) {
        int row = r * 16 + quad * 4 + i;
        float hh = fmaxf(acc[r][ci][i] + bgv, 0.0f);
        HsU[row * HS_STRIDE + col] = f2bf(hh);
      }
  }
  __syncthreads();

  // phase 3: pred head via MFMA (48-col padded), 6 tiles over 4 waves
  for (int tid = w; tid < 6; tid += 4) {
    int r2 = tid & 1, cb = tid >> 1;
    f32x4 acc2 = {0.f, 0.f, 0.f, 0.f};
#pragma unroll
    for (int kb = 0; kb < 4; ++kb) {
      int ko = kb * 32 + quad * 8;
      bf16x8 a = *reinterpret_cast<const bf16x8*>(HsU + (r2 * 16 + l16) * HS_STRIDE + ko);
      bf16x8 b = *reinterpret_cast<const bf16x8*>(Wpb + (cb * 16 + l16) * HID + ko);
      acc2 = __builtin_amdgcn_mfma_f32_16x16x32_bf16(a, b, acc2, 0, 0, 0);
    }
    int p = cb * 16 + l16;
    if (p < PREDN) {
      float bp = bpred[p];
#pragma unroll
      for (int i = 0; i < 4; ++i)
        Lg[(r2 * 16 + quad * 4 + i) * LG_STRIDE + p] = acc2[i] + bp;
    }
  }
  __syncthreads();

  // phase 4: log_softmax, half-wave per node
  int hw = t >> 5, l32 = lane & 31;
  for (int nn = hw; nn < BM; nn += 8) {
    float v0 = Lg[nn * LG_STRIDE + l32];
    float v1 = (l32 < 8) ? Lg[nn * LG_STRIDE + 32 + l32] : -1e30f;
    float m = fmaxf(v0, v1);
    for (int off = 16; off; off >>= 1) m = fmaxf(m, __shfl_xor(m, off, 32));
    float s = expf(v0 - m) + ((l32 < 8) ? expf(v1 - m) : 0.f);
    for (int off = 16; off; off >>= 1) s += __shfl_xor(s, off, 32);
    float lse = m + logf(s);
    int gn = node0 + nn;
    if (gn < N) {
      out[(size_t)gn * PREDN + l32] = v0 - lse;
      if (l32 < 8) out[(size_t)gn * PREDN + 32 + l32] = v1 - lse;
    }
  }
}

extern "C" void kernel_launch(void* const* d_in, const int* in_sizes, int n_in,
                              void* d_out, int out_size, void* d_ws, size_t ws_size,
                              hipStream_t stream) {
  const int*   node_index = (const int*)d_in[0];
  const float* node_feat  = (const float*)d_in[1];
  const int*   edge_index = (const int*)d_in[2];
  const float* emb        = (const float*)d_in[3];
  const float* Wmsg       = (const float*)d_in[4];
  const float* Wnode      = (const float*)d_in[5];
  const float* bg         = (const float*)d_in[6];
  const float* Wpred      = (const float*)d_in[7];
  const float* bpred      = (const float*)d_in[8];

  const int N = in_sizes[0];          // 100000
  const int E = in_sizes[2] / 2;      // 1600000

  const int nbucket = (N + (1 << BSHIFT) - 1) >> BSHIFT;       // 98 (<=128)
  int capb = E / nbucket + E / (4 * nbucket) + 2048;           // mean + 25% + slack
  capb = (capb + 15) & ~15;                                    // line-align (16 recs = 64B)

  int* gcur      = (int*)d_ws;                                 // nbucket*CUR_STRIDE
  int* region    = gcur + (size_t)nbucket * CUR_STRIDE;        // nbucket*capb (packed recs)
  int* csr_rows  = region + (size_t)nbucket * capb;            // nbucket*capb
  int* row_start = csr_rows + (size_t)nbucket * capb;          // N
  int* degv      = row_start + N;                              // N
  size_t off = (((size_t)(degv + N) - (size_t)d_ws) + 15) & ~(size_t)15;
  unsigned short* emb_bf = (unsigned short*)((char*)d_ws + off); // N*128
  unsigned short* Wcat   = emb_bf + (size_t)N * HID;             // 128*256
  unsigned short* Wpb    = Wcat + 128 * 256;                     // 48*128

  hipMemsetAsync(gcur, 0, (size_t)nbucket * CUR_STRIDE * sizeof(int), stream);

  const int ntile = (E + 256 * EPT - 1) / (256 * EPT);   // 391
  const int nconv = 416;
  const int nw    = 64;
  prologue_kernel<<<ntile + nconv + nw, 256, 0, stream>>>(
      edge_index, node_index, emb, Wmsg, Wnode, Wpred,
      gcur, region, emb_bf, Wcat, Wpb,
      E, N, nbucket, capb, ntile, nconv, nw);

  refine_kernel<<<nbucket, 256, 0, stream>>>(region, gcur, csr_rows,
                                             row_start, degv, N, capb);

  int nblk = (N + BM - 1) / BM;
  fused_node_kernel<<<nblk, 256, 0, stream>>>(csr_rows, row_start, degv,
                                              emb_bf, node_feat, Wcat, Wpb,
                                              bg, bpred, (float*)d_out, N);
}